// Round 12
// baseline (121.138 us; speedup 1.0000x reference)
//
#include <hip/hip_runtime.h>
#include <math.h>

#define EMB 256

typedef float f32x4 __attribute__((ext_vector_type(4)));

// ---------------------------------------------------------------------------
// K2: segment bounds via transition scan (indices are sorted).
// ---------------------------------------------------------------------------
__global__ void k_bounds_scan(const int* __restrict__ idx, int* __restrict__ seg_start,
                              int n, int g) {
    int i = blockIdx.x * blockDim.x + threadIdx.x;
    if (i >= n) return;
    const int a = idx[i];
    const int b = (i + 1 < n) ? idx[i + 1] : g;
    if (i == 0)
        for (int q = 0; q <= a; ++q) seg_start[q] = 0;
    for (int q = a + 1; q <= b; ++q) seg_start[q] = i + 1;
}

// ---------------------------------------------------------------------------
// K_fused: single pass over values with online softmax (R5/R9 core — best
// measured at 107.3 us). One block (4 waves) per segment, 4096 blocks
// dynamic. Wave w streams 8 consecutive rows per iteration (8 independent
// float4 loads in flight), shfl_xor butterflies broadcast each gate score to
// all lanes (rescale branch wave-uniform), ONE rescale per 8 rows.
// R11 A/B: plain cached loads instead of __builtin_nontemporal_load — the
// only hot-loop knob never isolated (entered bundled in R2-R4). If nt was
// capping read BW via LLC-bypass, this shows it; if null, stream is at floor.
// ---------------------------------------------------------------------------
__global__ void __launch_bounds__(256) k_fused(const float* __restrict__ vals,
                                               const float* __restrict__ gate_w,
                                               const float* __restrict__ gate_b,
                                               const int* __restrict__ seg_start,
                                               float* __restrict__ wvec) {
    const int g = blockIdx.x;
    const int start = seg_start[g], end = seg_start[g + 1];
    const int cnt = end - start;
    const int t = threadIdx.x;
    const int lane = t & 63, w = t >> 6;

    __shared__ float m_s[4], d_s[4];
    __shared__ float partial[4][EMB];

    if (cnt <= 0) {                 // empty segment -> exact zeros
        wvec[(size_t)g * EMB + t] = 0.0f;
        return;
    }

    const f32x4 gw = *reinterpret_cast<const f32x4*>(gate_w + lane * 4);
    const float gb = gate_b[0];

    float m = -INFINITY, d = 0.0f;
    f32x4 acc = {0.f, 0.f, 0.f, 0.f};

    for (int j = start + w * 8; j < end; j += 32) {
        // ---- issue up to 8 independent row loads (8 KB/wave in flight) ----
        f32x4 v[8];
        #pragma unroll
        for (int r = 0; r < 8; ++r) v[r] = (f32x4){0.f, 0.f, 0.f, 0.f};
        const float* p0 = vals + (size_t)j * EMB + lane * 4;
        if (j + 7 < end) {          // fast path (wave-uniform)
            #pragma unroll
            for (int r = 0; r < 8; ++r)
                v[r] = *reinterpret_cast<const f32x4*>(p0 + r * EMB);
        } else {
            #pragma unroll
            for (int r = 0; r < 8; ++r)
                if (j + r < end)
                    v[r] = *reinterpret_cast<const f32x4*>(p0 + r * EMB);
        }

        // ---- 8 gate dots, butterflies interleaved for ILP ----
        float s[8];
        #pragma unroll
        for (int r = 0; r < 8; ++r)
            s[r] = v[r].x * gw.x + v[r].y * gw.y + v[r].z * gw.z + v[r].w * gw.w;
        #pragma unroll
        for (int o = 1; o < 64; o <<= 1) {
            #pragma unroll
            for (int r = 0; r < 8; ++r) s[r] += __shfl_xor(s[r], o);
        }
        #pragma unroll
        for (int r = 0; r < 8; ++r) s[r] += gb;
        if (j + 7 >= end) {         // kill dead rows (tail only, wave-uniform)
            #pragma unroll
            for (int r = 1; r < 8; ++r)
                if (j + r >= end) s[r] = -INFINITY;
        }

        // ---- one online-softmax rescale per 8 rows ----
        float mx = s[0];
        #pragma unroll
        for (int r = 1; r < 8; ++r) mx = fmaxf(mx, s[r]);
        if (mx > m) {               // wave-uniform
            const float sc = __expf(m - mx);    // first iter: exp(-inf)=0
            d *= sc;
            acc.x *= sc; acc.y *= sc; acc.z *= sc; acc.w *= sc;
            m = mx;
        }
        float e[8];
        #pragma unroll
        for (int r = 0; r < 8; ++r) e[r] = __expf(s[r] - m);
        #pragma unroll
        for (int r = 0; r < 8; ++r) d += e[r];
        #pragma unroll
        for (int r = 0; r < 8; ++r) {
            acc.x += e[r] * v[r].x;
            acc.y += e[r] * v[r].y;
            acc.z += e[r] * v[r].z;
            acc.w += e[r] * v[r].w;
        }
    }

    // ---- cross-wave combine ----
    if (lane == 0) m_s[w] = m;      // waves with no rows contribute -inf
    __syncthreads();
    const float M = fmaxf(fmaxf(m_s[0], m_s[1]), fmaxf(m_s[2], m_s[3]));
    const float f = __expf(m - M);  // 0 for empty waves; M finite since cnt>0
    if (lane == 0) d_s[w] = d * f;
    acc.x *= f; acc.y *= f; acc.z *= f; acc.w *= f;
    *reinterpret_cast<f32x4*>(&partial[w][lane * 4]) = acc;
    __syncthreads();
    const float dt = d_s[0] + d_s[1] + d_s[2] + d_s[3];
    wvec[(size_t)g * EMB + t] =
        (partial[0][t] + partial[1][t] + partial[2][t] + partial[3][t]) / dt;
}

// ---------------------------------------------------------------------------
// K5: out[G,256] = wvec @ attn_w + (cnt>0) * attn_b
// 32x64 tiles -> 512 blocks = 2 blocks/CU (R9: 1/CU exposed all sync+staging
// latency). 256 threads, 2x4 register blocking. A_s padded to 68.
// ---------------------------------------------------------------------------
__global__ void __launch_bounds__(256) k_gemm(const float* __restrict__ A,
                                              const float* __restrict__ W,
                                              const float* __restrict__ bias,
                                              const int* __restrict__ seg_start,
                                              float* __restrict__ out) {
    __shared__ float A_s[32][68];
    __shared__ float B_s[64][64];
    const int bid = blockIdx.x;
    const int row0 = (bid >> 2) * 32;
    const int col0 = (bid & 3) * 64;
    const int t = threadIdx.x;
    const int ty = t >> 4, tx = t & 15;

    float acc[2][4] = {};

    for (int kc = 0; kc < EMB; kc += 64) {
        #pragma unroll
        for (int l = t; l < 32 * 16; l += 256) {       // A: 32x64 = 512 float4
            int r = l >> 4, c4 = (l & 15) << 2;
            *reinterpret_cast<float4*>(&A_s[r][c4]) =
                *reinterpret_cast<const float4*>(
                    A + (size_t)(row0 + r) * EMB + kc + c4);
        }
        #pragma unroll
        for (int l = t; l < 64 * 16; l += 256) {       // B: 64x64 = 1024 float4
            int r = l >> 4, c4 = (l & 15) << 2;
            *reinterpret_cast<float4*>(&B_s[r][c4]) =
                *reinterpret_cast<const float4*>(
                    W + (size_t)(kc + r) * EMB + col0 + c4);
        }
        __syncthreads();

        #pragma unroll
        for (int k = 0; k < 64; k += 4) {
            float a[2][4], b[4][4];
            #pragma unroll
            for (int i = 0; i < 2; ++i)
                *reinterpret_cast<float4*>(a[i]) =
                    *reinterpret_cast<const float4*>(&A_s[ty * 2 + i][k]);
            #pragma unroll
            for (int kk = 0; kk < 4; ++kk)
                *reinterpret_cast<float4*>(b[kk]) =
                    *reinterpret_cast<const float4*>(&B_s[k + kk][tx * 4]);
            #pragma unroll
            for (int i = 0; i < 2; ++i)
                #pragma unroll
                for (int kk = 0; kk < 4; ++kk)
                    #pragma unroll
                    for (int j = 0; j < 4; ++j)
                        acc[i][j] += a[i][kk] * b[kk][j];
        }
        __syncthreads();
    }

    const float4 b4 = *reinterpret_cast<const float4*>(bias + col0 + tx * 4);
    #pragma unroll
    for (int i = 0; i < 2; ++i) {
        const int r = row0 + ty * 2 + i;
        const float bs = (seg_start[r + 1] - seg_start[r]) > 0 ? 1.0f : 0.0f;
        float4 o;
        o.x = acc[i][0] + bs * b4.x;
        o.y = acc[i][1] + bs * b4.y;
        o.z = acc[i][2] + bs * b4.z;
        o.w = acc[i][3] + bs * b4.w;
        *reinterpret_cast<float4*>(out + (size_t)r * EMB + col0 + tx * 4) = o;
    }
}

// ---------------------------------------------------------------------------
extern "C" void kernel_launch(void* const* d_in, const int* in_sizes, int n_in,
                              void* d_out, int out_size, void* d_ws, size_t ws_size,
                              hipStream_t stream) {
    const float* vals   = (const float*)d_in[0];
    const int*   idx    = (const int*)d_in[1];
    const float* gate_w = (const float*)d_in[3];
    const float* gate_b = (const float*)d_in[4];
    const float* attn_w = (const float*)d_in[5];
    const float* attn_b = (const float*)d_in[6];
    float* out = (float*)d_out;

    const int n = in_sizes[1];          // number of nodes
    const int g = out_size / EMB;       // number of graphs (4096)

    // workspace layout (16B-aligned)
    int*   seg_start = (int*)d_ws;                         // g+1 ints
    float* wvec = (float*)((char*)d_ws + (((g + 1) * 4 + 15) & ~15)); // g*EMB floats

    k_bounds_scan<<<(n + 255) / 256, 256, 0, stream>>>(idx, seg_start, n, g);
    k_fused<<<g, 256, 0, stream>>>(vals, gate_w, gate_b, seg_start, wvec);
    k_gemm<<<(g / 32) * 4, 256, 0, stream>>>(wvec, attn_w, attn_b, seg_start, out);
}

// Round 13
// 106.858 us; speedup vs baseline: 1.1336x; 1.1336x over previous
//
#include <hip/hip_runtime.h>
#include <math.h>

#define EMB 256

typedef float f32x4 __attribute__((ext_vector_type(4)));   // native vector for nontemporal builtins

// ---------------------------------------------------------------------------
// K2: segment bounds via transition scan (indices are sorted).
// ---------------------------------------------------------------------------
__global__ void k_bounds_scan(const int* __restrict__ idx, int* __restrict__ seg_start,
                              int n, int g) {
    int i = blockIdx.x * blockDim.x + threadIdx.x;
    if (i >= n) return;
    const int a = idx[i];
    const int b = (i + 1 < n) ? idx[i + 1] : g;
    if (i == 0)
        for (int q = 0; q <= a; ++q) seg_start[q] = 0;
    for (int q = a + 1; q <= b; ++q) seg_start[q] = i + 1;
}

// ---------------------------------------------------------------------------
// K_fused: single pass over values with online softmax. Best measured config
// (107.3 us @ R10): one block (4 waves) per segment, 4096 blocks dynamic;
// wave w streams 8 consecutive rows/iter (8 independent nontemporal float4
// loads in flight — R12 A/B: nt vs cached is -13%, nt avoids LLC fill for
// this zero-reuse stream); shfl_xor butterflies broadcast gate scores to all
// lanes (rescale branch wave-uniform); ONE online-softmax rescale per 8 rows.
// Tested-and-rejected: persistence (R6 +15%), SW-pipeline (R8 null),
// epilogue-fused matvec (R9 +4%), 1-wave all-resident (R11 +3%).
// ---------------------------------------------------------------------------
__global__ void __launch_bounds__(256) k_fused(const float* __restrict__ vals,
                                               const float* __restrict__ gate_w,
                                               const float* __restrict__ gate_b,
                                               const int* __restrict__ seg_start,
                                               float* __restrict__ wvec) {
    const int g = blockIdx.x;
    const int start = seg_start[g], end = seg_start[g + 1];
    const int cnt = end - start;
    const int t = threadIdx.x;
    const int lane = t & 63, w = t >> 6;

    __shared__ float m_s[4], d_s[4];
    __shared__ float partial[4][EMB];

    if (cnt <= 0) {                 // empty segment -> exact zeros
        wvec[(size_t)g * EMB + t] = 0.0f;
        return;
    }

    const f32x4 gw = *reinterpret_cast<const f32x4*>(gate_w + lane * 4);
    const float gb = gate_b[0];

    float m = -INFINITY, d = 0.0f;
    f32x4 acc = {0.f, 0.f, 0.f, 0.f};

    for (int j = start + w * 8; j < end; j += 32) {
        // ---- issue up to 8 independent row loads (8 KB/wave in flight) ----
        f32x4 v[8];
        #pragma unroll
        for (int r = 0; r < 8; ++r) v[r] = (f32x4){0.f, 0.f, 0.f, 0.f};
        const float* p0 = vals + (size_t)j * EMB + lane * 4;
        if (j + 7 < end) {          // fast path (wave-uniform)
            #pragma unroll
            for (int r = 0; r < 8; ++r)
                v[r] = __builtin_nontemporal_load(
                    reinterpret_cast<const f32x4*>(p0 + r * EMB));
        } else {
            #pragma unroll
            for (int r = 0; r < 8; ++r)
                if (j + r < end)
                    v[r] = __builtin_nontemporal_load(
                        reinterpret_cast<const f32x4*>(p0 + r * EMB));
        }

        // ---- 8 gate dots, butterflies interleaved for ILP ----
        float s[8];
        #pragma unroll
        for (int r = 0; r < 8; ++r)
            s[r] = v[r].x * gw.x + v[r].y * gw.y + v[r].z * gw.z + v[r].w * gw.w;
        #pragma unroll
        for (int o = 1; o < 64; o <<= 1) {
            #pragma unroll
            for (int r = 0; r < 8; ++r) s[r] += __shfl_xor(s[r], o);
        }
        #pragma unroll
        for (int r = 0; r < 8; ++r) s[r] += gb;
        if (j + 7 >= end) {         // kill dead rows (tail only, wave-uniform)
            #pragma unroll
            for (int r = 1; r < 8; ++r)
                if (j + r >= end) s[r] = -INFINITY;
        }

        // ---- one online-softmax rescale per 8 rows ----
        float mx = s[0];
        #pragma unroll
        for (int r = 1; r < 8; ++r) mx = fmaxf(mx, s[r]);
        if (mx > m) {               // wave-uniform
            const float sc = __expf(m - mx);    // first iter: exp(-inf)=0
            d *= sc;
            acc.x *= sc; acc.y *= sc; acc.z *= sc; acc.w *= sc;
            m = mx;
        }
        float e[8];
        #pragma unroll
        for (int r = 0; r < 8; ++r) e[r] = __expf(s[r] - m);
        #pragma unroll
        for (int r = 0; r < 8; ++r) d += e[r];
        #pragma unroll
        for (int r = 0; r < 8; ++r) {
            acc.x += e[r] * v[r].x;
            acc.y += e[r] * v[r].y;
            acc.z += e[r] * v[r].z;
            acc.w += e[r] * v[r].w;
        }
    }

    // ---- cross-wave combine ----
    if (lane == 0) m_s[w] = m;      // waves with no rows contribute -inf
    __syncthreads();
    const float M = fmaxf(fmaxf(m_s[0], m_s[1]), fmaxf(m_s[2], m_s[3]));
    const float f = __expf(m - M);  // 0 for empty waves; M finite since cnt>0
    if (lane == 0) d_s[w] = d * f;
    acc.x *= f; acc.y *= f; acc.z *= f; acc.w *= f;
    *reinterpret_cast<f32x4*>(&partial[w][lane * 4]) = acc;
    __syncthreads();
    const float dt = d_s[0] + d_s[1] + d_s[2] + d_s[3];
    wvec[(size_t)g * EMB + t] =
        (partial[0][t] + partial[1][t] + partial[2][t] + partial[3][t]) / dt;
}

// ---------------------------------------------------------------------------
// K5: out[G,256] = wvec @ attn_w + (cnt>0) * attn_b
// 32x64 tiles -> 512 blocks = 2 blocks/CU (R9: 1/CU exposed all sync+staging
// latency; 2/CU overlaps it). 256 threads, 2x4 register blocking. A_s padded
// to 68 to de-conflict column reads.
// ---------------------------------------------------------------------------
__global__ void __launch_bounds__(256) k_gemm(const float* __restrict__ A,
                                              const float* __restrict__ W,
                                              const float* __restrict__ bias,
                                              const int* __restrict__ seg_start,
                                              float* __restrict__ out) {
    __shared__ float A_s[32][68];
    __shared__ float B_s[64][64];
    const int bid = blockIdx.x;
    const int row0 = (bid >> 2) * 32;
    const int col0 = (bid & 3) * 64;
    const int t = threadIdx.x;
    const int ty = t >> 4, tx = t & 15;

    float acc[2][4] = {};

    for (int kc = 0; kc < EMB; kc += 64) {
        #pragma unroll
        for (int l = t; l < 32 * 16; l += 256) {       // A: 32x64 = 512 float4
            int r = l >> 4, c4 = (l & 15) << 2;
            *reinterpret_cast<float4*>(&A_s[r][c4]) =
                *reinterpret_cast<const float4*>(
                    A + (size_t)(row0 + r) * EMB + kc + c4);
        }
        #pragma unroll
        for (int l = t; l < 64 * 16; l += 256) {       // B: 64x64 = 1024 float4
            int r = l >> 4, c4 = (l & 15) << 2;
            *reinterpret_cast<float4*>(&B_s[r][c4]) =
                *reinterpret_cast<const float4*>(
                    W + (size_t)(kc + r) * EMB + col0 + c4);
        }
        __syncthreads();

        #pragma unroll
        for (int k = 0; k < 64; k += 4) {
            float a[2][4], b[4][4];
            #pragma unroll
            for (int i = 0; i < 2; ++i)
                *reinterpret_cast<float4*>(a[i]) =
                    *reinterpret_cast<const float4*>(&A_s[ty * 2 + i][k]);
            #pragma unroll
            for (int kk = 0; kk < 4; ++kk)
                *reinterpret_cast<float4*>(b[kk]) =
                    *reinterpret_cast<const float4*>(&B_s[k + kk][tx * 4]);
            #pragma unroll
            for (int i = 0; i < 2; ++i)
                #pragma unroll
                for (int kk = 0; kk < 4; ++kk)
                    #pragma unroll
                    for (int j = 0; j < 4; ++j)
                        acc[i][j] += a[i][kk] * b[kk][j];
        }
        __syncthreads();
    }

    const float4 b4 = *reinterpret_cast<const float4*>(bias + col0 + tx * 4);
    #pragma unroll
    for (int i = 0; i < 2; ++i) {
        const int r = row0 + ty * 2 + i;
        const float bs = (seg_start[r + 1] - seg_start[r]) > 0 ? 1.0f : 0.0f;
        float4 o;
        o.x = acc[i][0] + bs * b4.x;
        o.y = acc[i][1] + bs * b4.y;
        o.z = acc[i][2] + bs * b4.z;
        o.w = acc[i][3] + bs * b4.w;
        *reinterpret_cast<float4*>(out + (size_t)r * EMB + col0 + tx * 4) = o;
    }
}

// ---------------------------------------------------------------------------
extern "C" void kernel_launch(void* const* d_in, const int* in_sizes, int n_in,
                              void* d_out, int out_size, void* d_ws, size_t ws_size,
                              hipStream_t stream) {
    const float* vals   = (const float*)d_in[0];
    const int*   idx    = (const int*)d_in[1];
    const float* gate_w = (const float*)d_in[3];
    const float* gate_b = (const float*)d_in[4];
    const float* attn_w = (const float*)d_in[5];
    const float* attn_b = (const float*)d_in[6];
    float* out = (float*)d_out;

    const int n = in_sizes[1];          // number of nodes
    const int g = out_size / EMB;       // number of graphs (4096)

    // workspace layout (16B-aligned)
    int*   seg_start = (int*)d_ws;                         // g+1 ints
    float* wvec = (float*)((char*)d_ws + (((g + 1) * 4 + 15) & ~15)); // g*EMB floats

    k_bounds_scan<<<(n + 255) / 256, 256, 0, stream>>>(idx, seg_start, n, g);
    k_fused<<<g, 256, 0, stream>>>(vals, gate_w, gate_b, seg_start, wvec);
    k_gemm<<<(g / 32) * 4, 256, 0, stream>>>(wvec, attn_w, attn_b, seg_start, out);
}